// Round 2
// baseline (541.305 us; speedup 1.0000x reference)
//
#include <hip/hip_runtime.h>
#include <hip/hip_bf16.h>

// fasterRCNN box decode + per-class argmax region pick — single fused kernel.
//
// Inputs (fp32): boxes (N,4), box_deltas (N,28), scores (N,7), im_info (3)
// Output (fp32, concat): pred_boxes (N*28), region_g (5), region_l (5)
//
// Work item = (row i, class c) pair p = i*7+c. deltas[p] and pred[p] are
// aligned float4 (row stride 112 B = 7*16 B) -> fully coalesced; scores flat
// index == p -> coalesced; boxes[i] shared by 7 consecutive lanes (L1).
//
// R1 changes vs R0 (82 us decode + ~160 us finalize/gap):
//  - ITEMS=4 explicit unroll, loads batched up front: R0 had VGPR=12 => fully
//    serialized dependent chain per iteration (latency-bound, 11% VALU, 29% HBM).
//  - finalize folded into decode via global atomicMax slots + last-block counter
//    (device-scope atomics, __threadfence before counter add). Winning region is
//    RECOMPUTED from inputs, so pred stores can be nontemporal (never re-read).
//  - hipMemsetAsync zeroes the 64B slot/counter area every graph replay.

#define THRESH_F 0.05f
#define TPB 256
#define ITEMS 4

typedef __attribute__((ext_vector_type(4))) float f4raw;

__device__ __forceinline__ unsigned map_float(unsigned bits) {
    // monotone map float bits -> unsigned (order-preserving)
    return (bits & 0x80000000u) ? ~bits : (bits | 0x80000000u);
}
__device__ __forceinline__ float unmap_float(unsigned m) {
    unsigned bits = (m & 0x80000000u) ? (m & 0x7FFFFFFFu) : ~m;
    return __uint_as_float(bits);
}

__device__ __forceinline__ float4 decode_one(float4 b, float4 d,
                                             float maxX, float maxY) {
    const float w  = b.z - b.x + 1.0f;
    const float h  = b.w - b.y + 1.0f;
    const float cx = b.x + 0.5f * w;
    const float cy = b.y + 0.5f * h;
    const float pcx = (d.x * 0.1f) * w + cx;
    const float pcy = (d.y * 0.1f) * h + cy;
    const float pw  = __expf(d.z * 0.2f) * w * 0.5f;
    const float ph  = __expf(d.w * 0.2f) * h * 0.5f;
    float4 o;
    o.x = fminf(fmaxf(pcx - pw, 0.0f), maxX);
    o.y = fminf(fmaxf(pcy - ph, 0.0f), maxY);
    o.z = fminf(fmaxf(pcx + pw, 0.0f), maxX);
    o.w = fminf(fmaxf(pcy + ph, 0.0f), maxY);
    return o;
}

__global__ __launch_bounds__(TPB) void fused_kernel(
    const float4* __restrict__ boxes,
    const float4* __restrict__ deltas,
    const float*  __restrict__ scores,
    const float*  __restrict__ im_info,
    float4*       __restrict__ pred,
    unsigned long long* __restrict__ gslots,   // 6 u64 in d_ws (zeroed)
    unsigned*           __restrict__ counter,  // 1 u32 in d_ws (zeroed)
    float*              __restrict__ regions,  // d_out + N*28
    int NP)
{
    __shared__ unsigned long long sbest[6];
    __shared__ int isLast;
    const int tid = threadIdx.x;
    if (tid < 6) sbest[tid] = 0ULL;
    __syncthreads();

    const float maxX = im_info[1] - 1.0f;   // W-1
    const float maxY = im_info[0] - 1.0f;   // H-1

    const int base = blockIdx.x * (TPB * ITEMS) + tid;

    int      p[ITEMS];
    bool     valid[ITEMS];
    unsigned ii[ITEMS], cc[ITEMS];
    float4   d[ITEMS], bx[ITEMS];
    float    sc[ITEMS];

    // Issue all loads up front: 4 independent chains -> MLP.
    #pragma unroll
    for (int k = 0; k < ITEMS; ++k) {
        p[k]     = base + k * TPB;
        valid[k] = (p[k] < NP);
        const int pc = valid[k] ? p[k] : 0;
        const unsigned up = (unsigned)pc;
        ii[k] = up / 7u;                 // magic-mul
        cc[k] = up - ii[k] * 7u;
        d[k]  = deltas[pc];
        bx[k] = boxes[ii[k]];
        sc[k] = scores[pc];
    }

    #pragma unroll
    for (int k = 0; k < ITEMS; ++k) {
        if (!valid[k]) continue;
        const float4 o = decode_one(bx[k], d[k], maxX, maxY);
        f4raw r; r.x = o.x; r.y = o.y; r.z = o.z; r.w = o.w;
        __builtin_nontemporal_store(r, (f4raw*)(pred + p[k]));

        if (cc[k] != 0u) {
            const float m = (sc[k] > THRESH_F) ? sc[k] : -1.0f;
            const unsigned mapped = map_float(__float_as_uint(m));
            const unsigned long long key =
                ((unsigned long long)mapped << 32) |
                (unsigned long long)(0xFFFFFFFFu - ii[k]);
            const int slot = (int)cc[k] - 1;
            const unsigned curhi = ((volatile unsigned*)sbest)[slot * 2 + 1];
            if (mapped >= curhi)
                atomicMax(&sbest[slot], key);
        }
    }
    __syncthreads();

    // Push block winners to global slots (device-scope atomics).
    if (tid < 6) {
        if (sbest[tid] != 0ULL)
            atomicMax(&gslots[tid], sbest[tid]);
        __threadfence();
    }
    __syncthreads();   // drains vmcnt: slot atomics complete before counter add

    if (tid == 0) {
        const unsigned prev = atomicAdd(counter, 1u);
        isLast = (prev == gridDim.x - 1u);
    }
    __syncthreads();

    if (isLast && tid == 0) {
        __threadfence();
        for (int g = 0; g < 2; ++g) {
            float bestSc = -1e30f;
            int bestJ = 0;
            unsigned bestIdx = 0;
            for (int j = 0; j < 3; ++j) {
                // atomicMax(x,0) == coherent atomic load
                const unsigned long long key = atomicMax(&gslots[g * 3 + j], 0ULL);
                const float s = unmap_float((unsigned)(key >> 32));
                const unsigned idx = 0xFFFFFFFFu - (unsigned)(key & 0xFFFFFFFFu);
                if (s > bestSc) { bestSc = s; bestJ = j; bestIdx = idx; } // first-max tie-break
            }
            const int c = g * 3 + bestJ + 1;
            const float4 b  = boxes[bestIdx];
            const float4 dd = deltas[bestIdx * 7u + (unsigned)c];
            const float4 o  = decode_one(b, dd, maxX, maxY);
            float* r = regions + g * 5;
            r[0] = o.x; r[1] = o.y; r[2] = o.z; r[3] = o.w; r[4] = bestSc;
        }
    }
}

extern "C" void kernel_launch(void* const* d_in, const int* in_sizes, int n_in,
                              void* d_out, int out_size, void* d_ws, size_t ws_size,
                              hipStream_t stream) {
    const float* boxes   = (const float*)d_in[0];
    const float* deltas  = (const float*)d_in[1];
    const float* scores  = (const float*)d_in[2];
    const float* im_info = (const float*)d_in[3];

    const int N  = in_sizes[0] / 4;      // 1,000,000
    const int NP = N * 7;                // 7,000,000 pairs

    float* out = (float*)d_out;
    float* regions = out + (size_t)N * 28;

    unsigned long long* gslots = (unsigned long long*)d_ws;           // 48 B
    unsigned* counter = (unsigned*)((char*)d_ws + 48);                // 4 B

    hipMemsetAsync(d_ws, 0, 64, stream);  // zero slots + counter each replay

    const int nblk = (NP + TPB * ITEMS - 1) / (TPB * ITEMS);          // 6836
    fused_kernel<<<nblk, TPB, 0, stream>>>(
        (const float4*)boxes, (const float4*)deltas, scores, im_info,
        (float4*)out, gslots, counter, regions, NP);
}

// Round 3
// 250.895 us; speedup vs baseline: 2.1575x; 2.1575x over previous
//
#include <hip/hip_runtime.h>
#include <hip/hip_bf16.h>

// fasterRCNN box decode + per-class argmax region pick.
// Inputs (fp32): boxes (N,4), box_deltas (N,28), scores (N,7), im_info (3)
// Output (fp32, concat): pred_boxes (N*28), region_g (5), region_l (5)
//
// Structure = R0 (passed, decode 82us) + ITEMS=4 load-batched unroll ONLY.
// R1's fusion extras (per-block __threadfence -> buffer_wbl2/inv L2 flushes,
// nontemporal stores, 6836 cold blocks) regressed 82->392us; reverted.
//
// Work item = (row i, class c) pair p = i*7+c:
//   deltas[p]/pred[p] aligned float4 (row stride 112B = 7*16B) -> coalesced
//   scores flat index == p -> coalesced; boxes[i] shared by 7 lanes (L1).
// Argmax key = (monotone(score)<<32) | (0xFFFFFFFF - i)  [first-index tie-break]
// LDS atomicMax per block w/ hi-word precheck; per-block winners -> d_ws;
// 1-block finalize reduces 2048x6 winners, gathers box from pred output.

#define THRESH_F 0.05f
#define TPB 256
#define ITEMS 4
#define BLOCKS 2048

__device__ __forceinline__ unsigned map_float(unsigned bits) {
    // monotone map float bits -> unsigned (order-preserving)
    return (bits & 0x80000000u) ? ~bits : (bits | 0x80000000u);
}

__device__ __forceinline__ float4 decode_one(float4 b, float4 d,
                                             float maxX, float maxY) {
    const float w  = b.z - b.x + 1.0f;
    const float h  = b.w - b.y + 1.0f;
    const float cx = b.x + 0.5f * w;
    const float cy = b.y + 0.5f * h;
    const float pcx = (d.x * 0.1f) * w + cx;
    const float pcy = (d.y * 0.1f) * h + cy;
    const float pw  = __expf(d.z * 0.2f) * w * 0.5f;
    const float ph  = __expf(d.w * 0.2f) * h * 0.5f;
    float4 o;
    o.x = fminf(fmaxf(pcx - pw, 0.0f), maxX);
    o.y = fminf(fmaxf(pcy - ph, 0.0f), maxY);
    o.z = fminf(fmaxf(pcx + pw, 0.0f), maxX);
    o.w = fminf(fmaxf(pcy + ph, 0.0f), maxY);
    return o;
}

__global__ __launch_bounds__(TPB) void decode_pick_kernel(
    const float4* __restrict__ boxes,
    const float4* __restrict__ deltas,
    const float*  __restrict__ scores,
    const float*  __restrict__ im_info,
    float4*       __restrict__ pred,
    unsigned long long* __restrict__ blockbest,
    int NP)
{
    __shared__ unsigned long long sbest[6];
    const int tid = threadIdx.x;
    if (tid < 6) sbest[tid] = 0ULL;
    __syncthreads();

    const float maxX = im_info[1] - 1.0f;   // W-1
    const float maxY = im_info[0] - 1.0f;   // H-1

    const int step = BLOCKS * TPB * ITEMS;  // per-sweep stride
    for (int base = blockIdx.x * (TPB * ITEMS) + tid; base < NP; base += step) {
        int      p[ITEMS];
        bool     valid[ITEMS];
        unsigned ii[ITEMS], cc[ITEMS];
        float4   d[ITEMS], bx[ITEMS];
        float    sc[ITEMS];

        // Batch all loads first: ITEMS independent chains -> MLP.
        #pragma unroll
        for (int k = 0; k < ITEMS; ++k) {
            p[k]     = base + k * TPB;
            valid[k] = (p[k] < NP);
            const int pc = valid[k] ? p[k] : 0;
            const unsigned up = (unsigned)pc;
            ii[k] = up / 7u;                 // magic-mul
            cc[k] = up - ii[k] * 7u;
            d[k]  = deltas[pc];
            bx[k] = boxes[ii[k]];
            sc[k] = scores[pc];
        }

        #pragma unroll
        for (int k = 0; k < ITEMS; ++k) {
            if (!valid[k]) continue;
            pred[p[k]] = decode_one(bx[k], d[k], maxX, maxY);

            if (cc[k] != 0u) {
                const float m = (sc[k] > THRESH_F) ? sc[k] : -1.0f;
                const unsigned mapped = map_float(__float_as_uint(m));
                const unsigned long long key =
                    ((unsigned long long)mapped << 32) |
                    (unsigned long long)(0xFFFFFFFFu - ii[k]);
                const int slot = (int)cc[k] - 1;
                // hi-word precheck skips most LDS atomics once sbest is warm
                const unsigned curhi = ((volatile unsigned*)sbest)[slot * 2 + 1];
                if (mapped >= curhi)
                    atomicMax(&sbest[slot], key);
            }
        }
    }
    __syncthreads();
    if (tid < 6)
        blockbest[(size_t)blockIdx.x * 6 + tid] = sbest[tid];
}

__global__ __launch_bounds__(TPB) void finalize_kernel(
    const unsigned long long* __restrict__ blockbest,
    int nblocks,
    const float* __restrict__ pred,
    float*       __restrict__ regions)   // d_out + N*28, 10 floats
{
    __shared__ unsigned long long red[TPB];
    __shared__ unsigned long long fin[6];
    const int tid = threadIdx.x;

    for (int slot = 0; slot < 6; ++slot) {
        unsigned long long k = 0ULL;
        for (int j = tid; j < nblocks; j += TPB) {
            unsigned long long v = blockbest[(size_t)j * 6 + slot];
            k = (v > k) ? v : k;
        }
        red[tid] = k;
        __syncthreads();
        for (int off = TPB / 2; off > 0; off >>= 1) {
            if (tid < off) {
                unsigned long long v = red[tid + off];
                if (v > red[tid]) red[tid] = v;
            }
            __syncthreads();
        }
        if (tid == 0) fin[slot] = red[0];
        __syncthreads();
    }

    if (tid == 0) {
        for (int g = 0; g < 2; ++g) {
            float scores_[3];
            unsigned idx_[3];
            float bestScore = -1e30f;
            int bestJ = 0;
            for (int j = 0; j < 3; ++j) {
                const unsigned long long key = fin[g * 3 + j];
                const unsigned hi = (unsigned)(key >> 32);
                const unsigned bits = (hi & 0x80000000u) ? (hi & 0x7FFFFFFFu) : ~hi;
                const float sc = __uint_as_float(bits);
                const unsigned idx = 0xFFFFFFFFu - (unsigned)(key & 0xFFFFFFFFu);
                scores_[j] = sc;
                idx_[j] = idx;
                if (sc > bestScore) { bestScore = sc; bestJ = j; }  // strict > : first-max
            }
            const int c = g * 3 + bestJ + 1;
            const unsigned i = idx_[bestJ];
            const float* pb = pred + (size_t)i * 28 + (size_t)c * 4;
            float* r = regions + g * 5;
            r[0] = pb[0];
            r[1] = pb[1];
            r[2] = pb[2];
            r[3] = pb[3];
            r[4] = scores_[bestJ];
        }
    }
}

extern "C" void kernel_launch(void* const* d_in, const int* in_sizes, int n_in,
                              void* d_out, int out_size, void* d_ws, size_t ws_size,
                              hipStream_t stream) {
    const float* boxes   = (const float*)d_in[0];
    const float* deltas  = (const float*)d_in[1];
    const float* scores  = (const float*)d_in[2];
    const float* im_info = (const float*)d_in[3];

    const int N  = in_sizes[0] / 4;      // 1,000,000
    const int NP = N * 7;                // 7,000,000 pairs

    float* out = (float*)d_out;
    float* regions = out + (size_t)N * 28;

    unsigned long long* blockbest = (unsigned long long*)d_ws;  // 2048*6*8 = 96 KB

    decode_pick_kernel<<<BLOCKS, TPB, 0, stream>>>(
        (const float4*)boxes, (const float4*)deltas, scores, im_info,
        (float4*)out, blockbest, NP);

    finalize_kernel<<<1, TPB, 0, stream>>>(blockbest, BLOCKS, out, regions);
}